// Round 1
// baseline (98.831 us; speedup 1.0000x reference)
//
#include <hip/hip_runtime.h>

// SRNormalization: layernorm with Quake fast-inverse-sqrt (bit trick + 1 Newton).
// x: [B=8, S=8192, H=1024] fp32 -> 65536 rows of 1024.
// One block (256 threads) per row; each thread owns 4 contiguous floats (float4).

#define H 1024
#define THREADS 256

__device__ __forceinline__ float fast_inv_sqrt_dev(float v) {
    // Must match reference bit-for-bit semantics: magic 0x5f3759df, one Newton iter.
    float x2 = v * 0.5f;
    int i = __float_as_int(v);
    i = 1597463007 - (i >> 1);
    float y = __int_as_float(i);
    return y * (1.5f - x2 * y * y);
}

__global__ __launch_bounds__(THREADS) void srnorm_kernel(
    const float* __restrict__ x,
    const float* __restrict__ weight,
    const float* __restrict__ bias,
    float* __restrict__ out)
{
    const int row = blockIdx.x;
    const int tid = threadIdx.x;
    const size_t base = (size_t)row * H;

    const float4 v = reinterpret_cast<const float4*>(x + base)[tid];

    float s  = v.x + v.y + v.z + v.w;
    float sq = v.x * v.x + v.y * v.y + v.z * v.z + v.w * v.w;

    // 64-lane wave butterfly reduce
    #pragma unroll
    for (int off = 32; off > 0; off >>= 1) {
        s  += __shfl_down(s,  off, 64);
        sq += __shfl_down(sq, off, 64);
    }

    __shared__ float ssum[4];
    __shared__ float ssq[4];
    const int wave = tid >> 6;
    const int lane = tid & 63;
    if (lane == 0) { ssum[wave] = s; ssq[wave] = sq; }
    __syncthreads();

    const float tot   = ssum[0] + ssum[1] + ssum[2] + ssum[3];
    const float totsq = ssq[0]  + ssq[1]  + ssq[2]  + ssq[3];

    const float mean = tot * (1.0f / (float)H);
    const float var  = totsq * (1.0f / (float)H) - mean * mean;
    const float sr   = fast_inv_sqrt_dev(var + 1e-5f);

    const float4 wv = reinterpret_cast<const float4*>(weight)[tid];
    const float4 bv = reinterpret_cast<const float4*>(bias)[tid];

    float4 o;
    o.x = wv.x * ((v.x - mean) * sr) + bv.x;
    o.y = wv.y * ((v.y - mean) * sr) + bv.y;
    o.z = wv.z * ((v.z - mean) * sr) + bv.z;
    o.w = wv.w * ((v.w - mean) * sr) + bv.w;

    reinterpret_cast<float4*>(out + base)[tid] = o;
}

extern "C" void kernel_launch(void* const* d_in, const int* in_sizes, int n_in,
                              void* d_out, int out_size, void* d_ws, size_t ws_size,
                              hipStream_t stream) {
    const float* x      = (const float*)d_in[0];
    const float* weight = (const float*)d_in[1];
    const float* bias   = (const float*)d_in[2];
    float* out = (float*)d_out;

    const int rows = in_sizes[0] / H;   // 65536
    srnorm_kernel<<<rows, THREADS, 0, stream>>>(x, weight, bias, out);
}

// Round 2
// 94.413 us; speedup vs baseline: 1.0468x; 1.0468x over previous
//
#include <hip/hip_runtime.h>

// SRNormalization: layernorm with Quake fast-inverse-sqrt (bit trick + 1 Newton).
// x: [B=8, S=8192, H=1024] fp32 -> 65536 rows of 1024.
// Structure: one WAVE (64 lanes) per row, 16 floats/lane as 4x float4.
//   - wave-only __shfl_xor butterfly reduce: no LDS, no __syncthreads
//   - persistent grid (2048 blocks x 4 waves = 8192 waves, 32 waves/CU), 8 rows/wave
//   - weight/bias fragments hoisted out of the row loop
//   - non-temporal load/store for the streamed x/out (read-once / write-once)

#define H 1024
#define THREADS 256
#define BLOCKS 2048

typedef float f32x4 __attribute__((ext_vector_type(4)));

__device__ __forceinline__ float fast_inv_sqrt_dev(float v) {
    // Must match reference bit-for-bit semantics: magic 0x5f3759df, one Newton iter.
    float x2 = v * 0.5f;
    int i = __float_as_int(v);
    i = 1597463007 - (i >> 1);
    float y = __int_as_float(i);
    return y * (1.5f - x2 * y * y);
}

__global__ __launch_bounds__(THREADS) void srnorm_kernel(
    const float* __restrict__ x,
    const float* __restrict__ weight,
    const float* __restrict__ bias,
    float* __restrict__ out,
    int rows)
{
    const int lane   = threadIdx.x & 63;
    const int wave   = blockIdx.x * (THREADS / 64) + (threadIdx.x >> 6);
    const int nwaves = gridDim.x * (THREADS / 64);

    // weight/bias are row-independent: load each lane's 4 fragments once.
    f32x4 wv[4], bv[4];
    #pragma unroll
    for (int k = 0; k < 4; ++k) {
        wv[k] = reinterpret_cast<const f32x4*>(weight)[lane + k * 64];
        bv[k] = reinterpret_cast<const f32x4*>(bias)[lane + k * 64];
    }

    for (int row = wave; row < rows; row += nwaves) {
        const f32x4* xr = reinterpret_cast<const f32x4*>(x + (size_t)row * H);
        f32x4*       orow = reinterpret_cast<f32x4*>(out + (size_t)row * H);

        f32x4 v[4];
        float s = 0.0f, sq = 0.0f;
        #pragma unroll
        for (int k = 0; k < 4; ++k) {
            v[k] = __builtin_nontemporal_load(xr + lane + k * 64);
            s  += v[k].x + v[k].y + v[k].z + v[k].w;
            sq += v[k].x * v[k].x + v[k].y * v[k].y
                + v[k].z * v[k].z + v[k].w * v[k].w;
        }

        // 64-lane butterfly: every lane ends with the full-row totals.
        #pragma unroll
        for (int off = 32; off > 0; off >>= 1) {
            s  += __shfl_xor(s,  off, 64);
            sq += __shfl_xor(sq, off, 64);
        }

        const float mean = s * (1.0f / (float)H);
        const float var  = sq * (1.0f / (float)H) - mean * mean;
        const float sr   = fast_inv_sqrt_dev(var + 1e-5f);

        #pragma unroll
        for (int k = 0; k < 4; ++k) {
            f32x4 o = wv[k] * ((v[k] - mean) * sr) + bv[k];
            __builtin_nontemporal_store(o, orow + lane + k * 64);
        }
    }
}

extern "C" void kernel_launch(void* const* d_in, const int* in_sizes, int n_in,
                              void* d_out, int out_size, void* d_ws, size_t ws_size,
                              hipStream_t stream) {
    const float* x      = (const float*)d_in[0];
    const float* weight = (const float*)d_in[1];
    const float* bias   = (const float*)d_in[2];
    float* out = (float*)d_out;

    const int rows = in_sizes[0] / H;   // 65536
    srnorm_kernel<<<BLOCKS, THREADS, 0, stream>>>(x, weight, bias, out, rows);
}

// Round 3
// 92.663 us; speedup vs baseline: 1.0666x; 1.0189x over previous
//
#include <hip/hip_runtime.h>

// SRNormalization: layernorm with Quake fast-inverse-sqrt (bit trick + 1 Newton).
// x: [B=8, S=8192, H=1024] fp32 -> 65536 rows of 1024.
// Structure: one WAVE (64 lanes) per row, 16 floats/lane as 4x float4.
//   - wave-only __shfl_xor butterfly reduce: no LDS, no __syncthreads
//   - persistent grid (2048 blocks x 4 waves = 8192 waves), 8 rows/wave
//   - 2-deep software pipeline: prefetch row i+1's loads before row i's reduce,
//     hiding HBM latency under the dependent shuffle chain (named vA/vB sets,
//     static indexing only)
//   - weight/bias fragments hoisted out of the row loop
//   - non-temporal load/store for the streamed x/out (read-once / write-once)

#define H 1024
#define THREADS 256
#define BLOCKS 2048

typedef float f32x4 __attribute__((ext_vector_type(4)));

__device__ __forceinline__ float fast_inv_sqrt_dev(float v) {
    // Must match reference bit-for-bit semantics: magic 0x5f3759df, one Newton iter.
    float x2 = v * 0.5f;
    int i = __float_as_int(v);
    i = 1597463007 - (i >> 1);
    float y = __int_as_float(i);
    return y * (1.5f - x2 * y * y);
}

__global__ __launch_bounds__(THREADS) void srnorm_kernel(
    const float* __restrict__ x,
    const float* __restrict__ weight,
    const float* __restrict__ bias,
    float* __restrict__ out,
    int rows)
{
    const int lane   = threadIdx.x & 63;
    const int wave   = blockIdx.x * (THREADS / 64) + (threadIdx.x >> 6);
    const int nwaves = gridDim.x * (THREADS / 64);

    // weight/bias are row-independent: load each lane's 4 fragments once.
    f32x4 wv[4], bv[4];
    #pragma unroll
    for (int k = 0; k < 4; ++k) {
        wv[k] = reinterpret_cast<const f32x4*>(weight)[lane + k * 64];
        bv[k] = reinterpret_cast<const f32x4*>(bias)[lane + k * 64];
    }

    auto load_row = [&](f32x4* v, int row) {
        const f32x4* xr = reinterpret_cast<const f32x4*>(x + (size_t)row * H);
        #pragma unroll
        for (int k = 0; k < 4; ++k)
            v[k] = __builtin_nontemporal_load(xr + lane + k * 64);
    };

    auto process_store = [&](const f32x4* v, int row) {
        float s = 0.0f, sq = 0.0f;
        #pragma unroll
        for (int k = 0; k < 4; ++k) {
            s  += v[k].x + v[k].y + v[k].z + v[k].w;
            sq += v[k].x * v[k].x + v[k].y * v[k].y
                + v[k].z * v[k].z + v[k].w * v[k].w;
        }
        #pragma unroll
        for (int off = 32; off > 0; off >>= 1) {
            s  += __shfl_xor(s,  off, 64);
            sq += __shfl_xor(sq, off, 64);
        }
        const float mean = s * (1.0f / (float)H);
        const float var  = sq * (1.0f / (float)H) - mean * mean;
        const float sr   = fast_inv_sqrt_dev(var + 1e-5f);

        f32x4* orow = reinterpret_cast<f32x4*>(out + (size_t)row * H);
        #pragma unroll
        for (int k = 0; k < 4; ++k) {
            f32x4 o = wv[k] * ((v[k] - mean) * sr) + bv[k];
            __builtin_nontemporal_store(o, orow + lane + k * 64);
        }
    };

    f32x4 vA[4], vB[4];
    int i = wave;
    if (i < rows) load_row(vA, i);

    while (i < rows) {
        const int j = i + nwaves;
        if (j < rows) load_row(vB, j);     // prefetch next row before reducing this one
        process_store(vA, i);
        i = j;
        if (i >= rows) break;

        const int k = i + nwaves;
        if (k < rows) load_row(vA, k);
        process_store(vB, i);
        i = k;
    }
}

extern "C" void kernel_launch(void* const* d_in, const int* in_sizes, int n_in,
                              void* d_out, int out_size, void* d_ws, size_t ws_size,
                              hipStream_t stream) {
    const float* x      = (const float*)d_in[0];
    const float* weight = (const float*)d_in[1];
    const float* bias   = (const float*)d_in[2];
    float* out = (float*)d_out;

    const int rows = in_sizes[0] / H;   // 65536
    srnorm_kernel<<<BLOCKS, THREADS, 0, stream>>>(x, weight, bias, out, rows);
}